// Round 6
// baseline (240.554 us; speedup 1.0000x reference)
//
#include <hip/hip_runtime.h>

typedef __attribute__((ext_vector_type(8))) short short8;
typedef __attribute__((ext_vector_type(8))) unsigned short ushort8;
typedef __attribute__((ext_vector_type(4))) float f32x4;

__device__ __forceinline__ float bf2f(unsigned short u) {
  union { unsigned int u; float f; } c; c.u = ((unsigned int)u) << 16; return c.f;
}
__device__ __forceinline__ unsigned short f2bf(float f) {
  union { float f; unsigned int u; } c; c.f = f;
  unsigned int x = c.u;
  return (unsigned short)((x + 0x7FFFu + ((x >> 16) & 1u)) >> 16);
}

#define GLD_LDS16(g, l)                                                        \
  __builtin_amdgcn_global_load_lds(                                            \
      (const __attribute__((address_space(1))) void*)(g),                      \
      (__attribute__((address_space(3))) void*)(l), 16, 0, 0)

// --------------------------------------------------- fused prep:
// blocks [0,4096): cast X fp32 -> bf16
// blocks [4096,4864): transpose+cast W[1024][3072] -> Wt[3072][1024] bf16
__global__ __launch_bounds__(256) void prep_kernel(
    const float* __restrict__ X, unsigned short* __restrict__ Xb,
    const float* __restrict__ W, unsigned short* __restrict__ Wt) {
  const int t = threadIdx.x;
  if (blockIdx.x < 4096) {
    long i = ((long)blockIdx.x * 256 + t) * 8;
    float4 a = *(const float4*)(X + i);
    float4 b = *(const float4*)(X + i + 4);
    ushort8 o;
    o[0] = f2bf(a.x); o[1] = f2bf(a.y); o[2] = f2bf(a.z); o[3] = f2bf(a.w);
    o[4] = f2bf(b.x); o[5] = f2bf(b.y); o[6] = f2bf(b.z); o[7] = f2bf(b.w);
    *(ushort8*)(Xb + i) = o;
  } else {
    const int bid = blockIdx.x - 4096;          // 768 blocks = 48 x 16
    const int f0 = (bid % 48) * 64;
    const int e0 = (bid / 48) * 64;
    __shared__ unsigned short tile[64][65];
    const int cg = (t & 15) * 4;
    const int r = t >> 4;
#pragma unroll
    for (int i = 0; i < 4; ++i) {
      int e = r + i * 16;
      float4 v = *(const float4*)(W + (long)(e0 + e) * 3072 + f0 + cg);
      tile[e][cg + 0] = f2bf(v.x);
      tile[e][cg + 1] = f2bf(v.y);
      tile[e][cg + 2] = f2bf(v.z);
      tile[e][cg + 3] = f2bf(v.w);
    }
    __syncthreads();
#pragma unroll
    for (int i = 0; i < 4; ++i) {
      int f = (t >> 4) + i * 16;
      int e = (t & 15) * 4;
      ushort4 o;
      o.x = tile[e + 0][f];
      o.y = tile[e + 1][f];
      o.z = tile[e + 2][f];
      o.w = tile[e + 3][f];
      *(ushort4*)(Wt + (long)(f0 + f) * 1024 + e0 + e) = o;
    }
  }
}

// ------------------------------------------- transpose V (bf16): QKV[b][s][2048+e] -> Vt[b][e][s]
// Also zeroes Lrow (row-sum accumulator for the fused softmax) — runs after GEMM1
// (which frees the Wtb region Lrow aliases) and before GEMM2 (which atomics into it).
__global__ __launch_bounds__(256) void transpose_v_kernel(
    const unsigned short* __restrict__ QKV, unsigned short* __restrict__ Vt,
    float* __restrict__ Lrow) {
  const int s0 = blockIdx.x * 64;  // 32
  const int e0 = blockIdx.y * 64;  // 16
  const int b = blockIdx.z;        // 4
  const int t = threadIdx.x;
  if (blockIdx.x == 0 && blockIdx.y == 0) {
    // zero this batch's 2048 row-sums (256 threads x 8 floats)
    float4 z = {0.f, 0.f, 0.f, 0.f};
    *(float4*)(Lrow + b * 2048 + t * 8) = z;
    *(float4*)(Lrow + b * 2048 + t * 8 + 4) = z;
  }
  const unsigned short* V = QKV + (long)b * 2048 * 3072 + 2048;
  unsigned short* VtB = Vt + (long)b * 1024 * 2048;
  __shared__ unsigned short tile[64][65];  // [s][e]
#pragma unroll
  for (int i = 0; i < 2; ++i) {
    int s = (t >> 3) + i * 32;
    int e = (t & 7) * 8;
    ushort8 v = *(const ushort8*)(V + (long)(s0 + s) * 3072 + e0 + e);
#pragma unroll
    for (int k = 0; k < 8; ++k) tile[s][e + k] = v[k];
  }
  __syncthreads();
#pragma unroll
  for (int i = 0; i < 2; ++i) {
    int e = (t >> 3) + i * 32;
    int s = (t & 7) * 8;
    ushort8 o;
#pragma unroll
    for (int k = 0; k < 8; ++k) o[k] = tile[s + k][e];
    *(ushort8*)(VtB + (long)(e0 + e) * 2048 + s0 + s) = o;
  }
}

// ---------------------------------------------------------------- GEMM C = A * B^T
// A: [M][K] bf16 (lda), B: [N][K] bf16 (ldb), C: [M][N] (ldc), batched via blockIdx.z.
// R3-verified m97 structure: 128x128 tile, BK=64, global_load_lds width-16,
// XOR-swizzled LDS, 16x16x32 MFMA.
// Round 6: (a) __launch_bounds__(256,4) — 64 VGPR + 64 AGPR = 128/thread fits
// 4 blocks/CU; (b) 8-row panel swizzle of (bx,by) so a resident block-cohort's
// A+B working set (~4 MB) fits one XCD L2, shortening the barrier-drain tail.
// MODE: 0 = plain bf16 out; 1 = bf16 exp(acc*alpha) out + row-sum atomicAdd to Lrow;
//       2 = fp32 out scaled by 1/Lrow[row].
template <int MODE>
__global__ __launch_bounds__(256, 4) void gemm_bt_kernel(
    const unsigned short* __restrict__ A, const unsigned short* __restrict__ B,
    void* __restrict__ Cv, int K, int lda, int ldb, int ldc,
    long sA, long sB, long sC, float alpha, float* __restrict__ Lrow) {
  constexpr int BM = 128, BN = 128, BK = 64;
  __shared__ __align__(16) unsigned short As[BM * BK];
  __shared__ __align__(16) unsigned short Bs[BN * BK];

  const int t = threadIdx.x;
  const int lane = t & 63;
  const int wave = t >> 6;
  const int quad = lane >> 4;
  const int mrow = lane & 15;
  const int wm = wave >> 1, wn = wave & 1;

  // 8-row panel swizzle (gridDim.y divisible by 8 for all call sites)
  const int nx = gridDim.x;
  const int lid = blockIdx.y * nx + blockIdx.x;
  const int panel = lid / (8 * nx);
  const int rem = lid - panel * 8 * nx;
  const int by = panel * 8 + (rem & 7);
  const int bx = rem >> 3;

  const int rowA0 = by * BM;
  const int rowB0 = bx * BN;
  const int b = blockIdx.z;
  const unsigned short* Ab = A + (long)b * sA;
  const unsigned short* Bb = B + (long)b * sB;

  f32x4 acc[4][4];
#pragma unroll
  for (int i = 0; i < 4; ++i)
#pragma unroll
    for (int j = 0; j < 4; ++j) {
      f32x4 z = {0.f, 0.f, 0.f, 0.f};
      acc[i][j] = z;
    }

  // staging geometry: slot s=(wave*4+j)*64+lane; row r=s>>3; chunk-col c2=s&7 (xor-swizzled)
  const int rbase = wave * 32 + (lane >> 3);
  const int c2 = lane & 7;

  for (int kt = 0; kt < K; kt += BK) {
#pragma unroll
    for (int j = 0; j < 4; ++j) {
      int r = rbase + j * 8;
      int c = c2 ^ (r & 7);
      GLD_LDS16(Ab + (long)(rowA0 + r) * lda + kt + c * 8, As + (wave * 4 + j) * 512);
      GLD_LDS16(Bb + (long)(rowB0 + r) * ldb + kt + c * 8, Bs + (wave * 4 + j) * 512);
    }
    __syncthreads();
#pragma unroll
    for (int ks = 0; ks < 2; ++ks) {
      short8 af[4], bfr[4];
#pragma unroll
      for (int i = 0; i < 4; ++i) {
        int rA = wm * 64 + i * 16 + mrow;
        int cc = ks * 4 + quad;
        af[i] = *(const short8*)(As + (rA * 8 + (cc ^ (rA & 7))) * 8);
        int rB = wn * 64 + i * 16 + mrow;
        bfr[i] = *(const short8*)(Bs + (rB * 8 + (cc ^ (rB & 7))) * 8);
      }
#pragma unroll
      for (int mt = 0; mt < 4; ++mt)
#pragma unroll
        for (int nt = 0; nt < 4; ++nt)
          acc[mt][nt] = __builtin_amdgcn_mfma_f32_16x16x32_bf16(
              af[mt], bfr[nt], acc[mt][nt], 0, 0, 0);
    }
    __syncthreads();
  }

  // epilogue — C/D layout (m89-verified): col = lane&15, row = quad*4 + reg
  const int m_base = rowA0 + wm * 64;
  const int n_base = rowB0 + wn * 64;
  const long cb = (long)b * sC;

  if constexpr (MODE == 0) {
#pragma unroll
    for (int mt = 0; mt < 4; ++mt)
#pragma unroll
      for (int nt = 0; nt < 4; ++nt)
#pragma unroll
        for (int i = 0; i < 4; ++i) {
          int row = m_base + mt * 16 + quad * 4 + i;
          int col = n_base + nt * 16 + mrow;
          ((unsigned short*)Cv)[cb + (long)row * ldc + col] =
              f2bf(acc[mt][nt][i] * alpha);
        }
  } else if constexpr (MODE == 1) {
    // E = exp(acc*alpha), store bf16; accumulate row sums -> Lrow
    float p[4][4];
#pragma unroll
    for (int mt = 0; mt < 4; ++mt)
#pragma unroll
      for (int i = 0; i < 4; ++i) p[mt][i] = 0.f;
#pragma unroll
    for (int mt = 0; mt < 4; ++mt)
#pragma unroll
      for (int nt = 0; nt < 4; ++nt)
#pragma unroll
        for (int i = 0; i < 4; ++i) {
          int row = m_base + mt * 16 + quad * 4 + i;
          int col = n_base + nt * 16 + mrow;
          float e = __expf(acc[mt][nt][i] * alpha);
          ((unsigned short*)Cv)[cb + (long)row * ldc + col] = f2bf(e);
          p[mt][i] += e;
        }
    // reduce partials over the 16 mrow lanes (lane bits 0..3)
#pragma unroll
    for (int off = 1; off < 16; off <<= 1)
#pragma unroll
      for (int mt = 0; mt < 4; ++mt)
#pragma unroll
        for (int i = 0; i < 4; ++i)
          p[mt][i] += __shfl_xor(p[mt][i], off, 64);
    if (mrow == 0) {
#pragma unroll
      for (int mt = 0; mt < 4; ++mt)
#pragma unroll
        for (int i = 0; i < 4; ++i) {
          int row = m_base + mt * 16 + quad * 4 + i;
          atomicAdd(&Lrow[b * 2048 + row], p[mt][i]);
        }
    }
  } else {
    // fp32 out, scaled by 1/Lrow[row]
#pragma unroll
    for (int mt = 0; mt < 4; ++mt)
#pragma unroll
      for (int i = 0; i < 4; ++i) {
        int row = m_base + mt * 16 + quad * 4 + i;
        float inv = 1.0f / Lrow[b * 2048 + row];
#pragma unroll
        for (int nt = 0; nt < 4; ++nt) {
          int col = n_base + nt * 16 + mrow;
          ((float*)Cv)[cb + (long)row * ldc + col] = acc[mt][nt][i] * inv;
        }
      }
  }
}

// ---------------------------------------------------------------- launch
extern "C" void kernel_launch(void* const* d_in, const int* in_sizes, int n_in,
                              void* d_out, int out_size, void* d_ws, size_t ws_size,
                              hipStream_t stream) {
  const float* X = (const float*)d_in[0];  // [4,2048,1024] fp32
  const float* W = (const float*)d_in[1];  // [1024,3072] fp32
  float* out = (float*)d_out;              // [4,2048,1024] fp32

  char* ws = (char*)d_ws;
  unsigned short* Xb  = (unsigned short*)(ws);                 // 8192x1024 bf16   (16 MiB)
  unsigned short* Wtb = (unsigned short*)(ws + 16777216);      // 3072x1024 bf16   ( 6 MiB)
  unsigned short* QKV = (unsigned short*)(ws + 23068672);      // 8192x3072 bf16   (48 MiB)
  unsigned short* Vt  = (unsigned short*)(ws + 73400320);      // 4x1024x2048 bf16 (16 MiB)
  unsigned short* Sb  = (unsigned short*)(ws + 90177536);      // 4x2048x2048 bf16 (32 MiB)
  // L reuses the Wtb region (free after GEMM1): 4x2048 fp32 = 32 KiB
  float* Lrow = (float*)(ws + 16777216);

  // 1. fused cast + transpose prep
  prep_kernel<<<4864, 256, 0, stream>>>(X, Xb, W, Wtb);

  // 2. QKV = Xb @ Wtb^T   [8192 x 3072], K=1024
  gemm_bt_kernel<0><<<dim3(24, 64, 1), 256, 0, stream>>>(
      Xb, Wtb, QKV, 1024, 1024, 1024, 3072, 0L, 0L, 0L, 1.0f, nullptr);

  // 3. Vt[b][e][s] = V[b][s][e]; also zeroes Lrow
  transpose_v_kernel<<<dim3(32, 16, 4), 256, 0, stream>>>(QKV, Vt, Lrow);

  // 4. E = exp(Q @ K^T / 32) per batch [2048 x 2048], K=1024; row sums -> Lrow
  gemm_bt_kernel<1><<<dim3(16, 16, 4), 256, 0, stream>>>(
      QKV, QKV + 1024, Sb, 1024, 3072, 3072, 2048,
      (long)2048 * 3072, (long)2048 * 3072, (long)2048 * 2048, 0.03125f, Lrow);

  // 5. O = (E @ Vt^T) / L  per batch  [2048 x 1024], K=2048 -> fp32 out
  gemm_bt_kernel<2><<<dim3(8, 16, 4), 256, 0, stream>>>(
      Sb, Vt, out, 2048, 2048, 2048, 1024,
      (long)2048 * 2048, (long)1024 * 2048, (long)2048 * 1024, 1.0f, Lrow);
}

// Round 7
// 232.349 us; speedup vs baseline: 1.0353x; 1.0353x over previous
//
#include <hip/hip_runtime.h>

typedef __attribute__((ext_vector_type(8))) short short8;
typedef __attribute__((ext_vector_type(8))) unsigned short ushort8;
typedef __attribute__((ext_vector_type(4))) float f32x4;

__device__ __forceinline__ float bf2f(unsigned short u) {
  union { unsigned int u; float f; } c; c.u = ((unsigned int)u) << 16; return c.f;
}
__device__ __forceinline__ unsigned short f2bf(float f) {
  union { float f; unsigned int u; } c; c.f = f;
  unsigned int x = c.u;
  return (unsigned short)((x + 0x7FFFu + ((x >> 16) & 1u)) >> 16);
}

#define GLD_LDS16(g, l)                                                        \
  __builtin_amdgcn_global_load_lds(                                            \
      (const __attribute__((address_space(1))) void*)(g),                      \
      (__attribute__((address_space(3))) void*)(l), 16, 0, 0)

// --------------------------------------------------- fused prep:
// blocks [0,4096): cast X fp32 -> bf16
// blocks [4096,4864): transpose+cast W[1024][3072] -> Wt[3072][1024] bf16
__global__ __launch_bounds__(256) void prep_kernel(
    const float* __restrict__ X, unsigned short* __restrict__ Xb,
    const float* __restrict__ W, unsigned short* __restrict__ Wt) {
  const int t = threadIdx.x;
  if (blockIdx.x < 4096) {
    long i = ((long)blockIdx.x * 256 + t) * 8;
    float4 a = *(const float4*)(X + i);
    float4 b = *(const float4*)(X + i + 4);
    ushort8 o;
    o[0] = f2bf(a.x); o[1] = f2bf(a.y); o[2] = f2bf(a.z); o[3] = f2bf(a.w);
    o[4] = f2bf(b.x); o[5] = f2bf(b.y); o[6] = f2bf(b.z); o[7] = f2bf(b.w);
    *(ushort8*)(Xb + i) = o;
  } else {
    const int bid = blockIdx.x - 4096;          // 768 blocks = 48 x 16
    const int f0 = (bid % 48) * 64;
    const int e0 = (bid / 48) * 64;
    __shared__ unsigned short tile[64][65];
    const int cg = (t & 15) * 4;
    const int r = t >> 4;
#pragma unroll
    for (int i = 0; i < 4; ++i) {
      int e = r + i * 16;
      float4 v = *(const float4*)(W + (long)(e0 + e) * 3072 + f0 + cg);
      tile[e][cg + 0] = f2bf(v.x);
      tile[e][cg + 1] = f2bf(v.y);
      tile[e][cg + 2] = f2bf(v.z);
      tile[e][cg + 3] = f2bf(v.w);
    }
    __syncthreads();
#pragma unroll
    for (int i = 0; i < 4; ++i) {
      int f = (t >> 4) + i * 16;
      int e = (t & 15) * 4;
      ushort4 o;
      o.x = tile[e + 0][f];
      o.y = tile[e + 1][f];
      o.z = tile[e + 2][f];
      o.w = tile[e + 3][f];
      *(ushort4*)(Wt + (long)(f0 + f) * 1024 + e0 + e) = o;
    }
  }
}

// ---------------------------------------------------------------- GEMM C = A * B^T
// R5-verified m97 structure: 128x128 tile, BK=64, global_load_lds width-16,
// XOR-swizzled LDS, 16x16x32 MFMA, (256,2) launch bounds, no grid swizzle.
// MODE 0 (qkv): bx<16 -> bf16 C to QKV; bx>=16 -> transposed bf16 to Vt (LDS re-tile).
// MODE 1 (score): bf16 exp(acc*alpha) + row-sum atomicAdd into Lrow.
// MODE 2 (out): fp32 C scaled by 1/Lrow[row].
template <int MODE>
__device__ __forceinline__ void gemm_body(
    const unsigned short* __restrict__ A, const unsigned short* __restrict__ B,
    void* __restrict__ Cv, int K, int lda, int ldb, int ldc,
    long sA, long sB, long sC, float alpha, float* __restrict__ Lrow,
    unsigned short* __restrict__ Vt) {
  constexpr int BM = 128, BN = 128, BK = 64;
  __shared__ __align__(16) unsigned short smem[BM * BK + BN * BK];  // As | Bs, 32 KB
  unsigned short* As = smem;
  unsigned short* Bs = smem + BM * BK;

  const int t = threadIdx.x;
  const int lane = t & 63;
  const int wave = t >> 6;
  const int quad = lane >> 4;
  const int mrow = lane & 15;
  const int wm = wave >> 1, wn = wave & 1;

  const int bx = blockIdx.x, by = blockIdx.y;
  const int rowA0 = by * BM;
  const int rowB0 = bx * BN;
  const int b = blockIdx.z;
  const unsigned short* Ab = A + (long)b * sA;
  const unsigned short* Bb = B + (long)b * sB;

  f32x4 acc[4][4];
#pragma unroll
  for (int i = 0; i < 4; ++i)
#pragma unroll
    for (int j = 0; j < 4; ++j) {
      f32x4 z = {0.f, 0.f, 0.f, 0.f};
      acc[i][j] = z;
    }

  const int rbase = wave * 32 + (lane >> 3);
  const int c2 = lane & 7;

  for (int kt = 0; kt < K; kt += BK) {
#pragma unroll
    for (int j = 0; j < 4; ++j) {
      int r = rbase + j * 8;
      int c = c2 ^ (r & 7);
      GLD_LDS16(Ab + (long)(rowA0 + r) * lda + kt + c * 8, As + (wave * 4 + j) * 512);
      GLD_LDS16(Bb + (long)(rowB0 + r) * ldb + kt + c * 8, Bs + (wave * 4 + j) * 512);
    }
    __syncthreads();
#pragma unroll
    for (int ks = 0; ks < 2; ++ks) {
      short8 af[4], bfr[4];
#pragma unroll
      for (int i = 0; i < 4; ++i) {
        int rA = wm * 64 + i * 16 + mrow;
        int cc = ks * 4 + quad;
        af[i] = *(const short8*)(As + (rA * 8 + (cc ^ (rA & 7))) * 8);
        int rB = wn * 64 + i * 16 + mrow;
        bfr[i] = *(const short8*)(Bs + (rB * 8 + (cc ^ (rB & 7))) * 8);
      }
#pragma unroll
      for (int mt = 0; mt < 4; ++mt)
#pragma unroll
        for (int nt = 0; nt < 4; ++nt)
          acc[mt][nt] = __builtin_amdgcn_mfma_f32_16x16x32_bf16(
              af[mt], bfr[nt], acc[mt][nt], 0, 0, 0);
    }
    __syncthreads();
  }

  // epilogue — C/D layout (m89-verified): col = lane&15, row = quad*4 + reg
  const int m_base = rowA0 + wm * 64;
  const int n_base = rowB0 + wn * 64;
  const long cb = (long)b * sC;

  if constexpr (MODE == 0) {
    if (bx < 16) {
      // Q/K columns: plain bf16 write into QKV
#pragma unroll
      for (int mt = 0; mt < 4; ++mt)
#pragma unroll
        for (int nt = 0; nt < 4; ++nt)
#pragma unroll
          for (int i = 0; i < 4; ++i) {
            int row = m_base + mt * 16 + quad * 4 + i;
            int col = n_base + nt * 16 + mrow;
            ((unsigned short*)Cv)[cb + (long)row * ldc + col] = f2bf(acc[mt][nt][i]);
          }
    } else {
      // V columns: transpose via LDS (smem = full 128x128 bf16 tile), write Vt.
      // swz(x) = ((x&7)<<4) ^ (((x>>3)&3)<<3): <=2-way conflicts both phases,
      // preserves 8-short contiguity for b128 reads.
#pragma unroll
      for (int mt = 0; mt < 4; ++mt)
#pragma unroll
        for (int nt = 0; nt < 4; ++nt)
#pragma unroll
          for (int i = 0; i < 4; ++i) {
            int r = wm * 64 + mt * 16 + quad * 4 + i;      // tile-local s
            int cL = wn * 64 + nt * 16 + mrow;             // tile-local e
            int swz = ((cL & 7) << 4) ^ (((cL >> 3) & 3) << 3);
            smem[cL * 128 + (r ^ swz)] = f2bf(acc[mt][nt][i]);
          }
      __syncthreads();
      const int batch = by >> 4;
      const int s_base = (by & 15) * 128;
      const int e_base = (bx - 16) * 128;
      unsigned short* VtB = Vt + (long)batch * 1024 * 2048;
#pragma unroll
      for (int rnd = 0; rnd < 8; ++rnd) {
        int e = (t >> 4) + rnd * 16;
        int s = (t & 15) * 8;
        int swz = ((e & 7) << 4) ^ (((e >> 3) & 3) << 3);
        ushort8 v = *(const ushort8*)(smem + e * 128 + (s ^ swz));
        *(ushort8*)(VtB + (long)(e_base + e) * 2048 + s_base + s) = v;
      }
    }
  } else if constexpr (MODE == 1) {
    // E = exp(acc*alpha), store bf16; accumulate row sums -> Lrow
    float p[4][4];
#pragma unroll
    for (int mt = 0; mt < 4; ++mt)
#pragma unroll
      for (int i = 0; i < 4; ++i) p[mt][i] = 0.f;
#pragma unroll
    for (int mt = 0; mt < 4; ++mt)
#pragma unroll
      for (int nt = 0; nt < 4; ++nt)
#pragma unroll
        for (int i = 0; i < 4; ++i) {
          int row = m_base + mt * 16 + quad * 4 + i;
          int col = n_base + nt * 16 + mrow;
          float e = __expf(acc[mt][nt][i] * alpha);
          ((unsigned short*)Cv)[cb + (long)row * ldc + col] = f2bf(e);
          p[mt][i] += e;
        }
#pragma unroll
    for (int off = 1; off < 16; off <<= 1)
#pragma unroll
      for (int mt = 0; mt < 4; ++mt)
#pragma unroll
        for (int i = 0; i < 4; ++i)
          p[mt][i] += __shfl_xor(p[mt][i], off, 64);
    if (mrow == 0) {
#pragma unroll
      for (int mt = 0; mt < 4; ++mt)
#pragma unroll
        for (int i = 0; i < 4; ++i) {
          int row = m_base + mt * 16 + quad * 4 + i;
          atomicAdd(&Lrow[b * 2048 + row], p[mt][i]);
        }
    }
  } else {
    // fp32 out, scaled by 1/Lrow[row]
#pragma unroll
    for (int mt = 0; mt < 4; ++mt)
#pragma unroll
      for (int i = 0; i < 4; ++i) {
        int row = m_base + mt * 16 + quad * 4 + i;
        float inv = 1.0f / Lrow[b * 2048 + row];
#pragma unroll
        for (int nt = 0; nt < 4; ++nt) {
          int col = n_base + nt * 16 + mrow;
          ((float*)Cv)[cb + (long)row * ldc + col] = acc[mt][nt][i] * inv;
        }
      }
  }
}

// distinct names so rocprof separates the three GEMMs
__global__ __launch_bounds__(256, 2) void qkv_gemm_kernel(
    const unsigned short* __restrict__ A, const unsigned short* __restrict__ B,
    void* __restrict__ Cv, int K, int lda, int ldb, int ldc,
    long sA, long sB, long sC, float alpha, float* __restrict__ Lrow,
    unsigned short* __restrict__ Vt) {
  gemm_body<0>(A, B, Cv, K, lda, ldb, ldc, sA, sB, sC, alpha, Lrow, Vt);
}
__global__ __launch_bounds__(256, 2) void score_gemm_kernel(
    const unsigned short* __restrict__ A, const unsigned short* __restrict__ B,
    void* __restrict__ Cv, int K, int lda, int ldb, int ldc,
    long sA, long sB, long sC, float alpha, float* __restrict__ Lrow,
    unsigned short* __restrict__ Vt) {
  gemm_body<1>(A, B, Cv, K, lda, ldb, ldc, sA, sB, sC, alpha, Lrow, Vt);
}
__global__ __launch_bounds__(256, 2) void out_gemm_kernel(
    const unsigned short* __restrict__ A, const unsigned short* __restrict__ B,
    void* __restrict__ Cv, int K, int lda, int ldb, int ldc,
    long sA, long sB, long sC, float alpha, float* __restrict__ Lrow,
    unsigned short* __restrict__ Vt) {
  gemm_body<2>(A, B, Cv, K, lda, ldb, ldc, sA, sB, sC, alpha, Lrow, Vt);
}

// ---------------------------------------------------------------- launch
extern "C" void kernel_launch(void* const* d_in, const int* in_sizes, int n_in,
                              void* d_out, int out_size, void* d_ws, size_t ws_size,
                              hipStream_t stream) {
  const float* X = (const float*)d_in[0];  // [4,2048,1024] fp32
  const float* W = (const float*)d_in[1];  // [1024,3072] fp32
  float* out = (float*)d_out;              // [4,2048,1024] fp32

  char* ws = (char*)d_ws;
  unsigned short* Xb  = (unsigned short*)(ws);                 // 8192x1024 bf16   (16 MiB)
  unsigned short* Wtb = (unsigned short*)(ws + 16777216);      // 3072x1024 bf16   ( 6 MiB)
  unsigned short* QKV = (unsigned short*)(ws + 23068672);      // 8192x3072 bf16   (48 MiB; V cols unused)
  unsigned short* Vt  = (unsigned short*)(ws + 73400320);      // 4x1024x2048 bf16 (16 MiB)
  unsigned short* Sb  = (unsigned short*)(ws + 90177536);      // 4x2048x2048 bf16 (32 MiB)
  // Lrow reuses the Wtb region (dead after qkv_gemm): 4x2048 fp32 = 32 KiB
  float* Lrow = (float*)(ws + 16777216);

  // 1. fused cast + transpose prep
  prep_kernel<<<4864, 256, 0, stream>>>(X, Xb, W, Wtb);

  // 2. QKV = Xb @ Wtb^T  [8192 x 3072], K=1024; Q,K -> QKV, V -> Vt (transposed)
  qkv_gemm_kernel<<<dim3(24, 64, 1), 256, 0, stream>>>(
      Xb, Wtb, QKV, 1024, 1024, 1024, 3072, 0L, 0L, 0L, 1.0f, nullptr, Vt);

  // 3. zero the row-sum accumulator (Wtb region is dead now)
  hipMemsetAsync(Lrow, 0, 4 * 2048 * sizeof(float), stream);

  // 4. E = exp(Q @ K^T / 32) per batch [2048 x 2048], K=1024; row sums -> Lrow
  score_gemm_kernel<<<dim3(16, 16, 4), 256, 0, stream>>>(
      QKV, QKV + 1024, Sb, 1024, 3072, 3072, 2048,
      (long)2048 * 3072, (long)2048 * 3072, (long)2048 * 2048, 0.03125f, Lrow, nullptr);

  // 5. O = (E @ Vt^T) / L  per batch  [2048 x 1024], K=2048 -> fp32 out
  out_gemm_kernel<<<dim3(8, 16, 4), 256, 0, stream>>>(
      Sb, Vt, out, 2048, 2048, 2048, 1024,
      (long)2048 * 2048, (long)1024 * 2048, (long)2048 * 1024, 1.0f, Lrow, nullptr);
}